// Round 3
// baseline (757.810 us; speedup 1.0000x reference)
//
#include <hip/hip_runtime.h>

// Problem constants (from reference):
#define CCH 3
#define HH 224
#define WW 220
#define NP 20          // num patches (4 x 5)
#define HID 32

#define W4     (WW / 4)            // 55 float4 per image row
#define IMG4   (CCH * HH * W4)     // 36960 float4 per image (591,360 B)
#define NU     (IMG4 / 2)          // 18480 2-float4 (32 B) units per image
#define NT     512                 // threads per block (8 waves)
#define FULLIT (NU / NT)           // 36 full iterations
#define TAILT  (NU - FULLIT*NT)    // 48 tail units
#define INV_N  (1.0f / 7392.0f)    // 1 / (C*PH*PW)

typedef float v4f __attribute__((ext_vector_type(4)));

// Exact integer helpers (verified over the required ranges):
//   row = idx/55 : (idx*38131)>>21  exact for idx < 39568 (max 36959)
//   pr  = h/56   : (h*293)>>14      exact for h   < 672   (max 223)
//   pc  = c4/11  : (c4*94)>>10      exact for c4  < 99    (max 54)
// A float4 never crosses a bin boundary: rows are 55 float4 (220/4) and a
// patch column is exactly 11 float4, so all 4 floats share one (row, pc).
__device__ __forceinline__ unsigned bin_of(unsigned idx)
{
    const unsigned row = (idx * 38131u) >> 21;     // flat row 0..671
    const unsigned c4  = idx - row * 55u;          // float4 col 0..54
    unsigned h = row;                              // h = row % 224
    h = h >= 448u ? h - 448u : (h >= 224u ? h - 224u : h);
    const unsigned pr = (h * 293u) >> 14;          // patch row 0..3
    const unsigned pc = (c4 * 94u) >> 10;          // patch col 0..4
    return pr * 5u + pc;
}

// One block per image, 512 threads, ONE forward-linear stream per block.
// This round's single lever vs R2 (same structure, absmax 0.0): the memory
// path. Plain loads (NO nontemporal -- the nt policy was common to all three
// ~3.6 TB/s rounds and is the untested suspect; m13's 6.29 TB/s copy uses
// plain float4 loads), 32 B/lane per iteration (wave-load = 2 KB dense,
// 128-B aligned), unroll 4 = 8 dwordx4 in flight per wave.
// Per-element patch bin via exact magic division; accumulate in per-thread
// LDS slots bins[bin][tid] (bank = tid%32: lane l & l+32 pair = 2-way = free).
__global__ __launch_bounds__(NT) void fused_patch_nam_kernel(
    const float* __restrict__ x,
    const float* __restrict__ w1, const float* __restrict__ b1,
    const float* __restrict__ w2, const float* __restrict__ b2,
    float* __restrict__ out, int B)
{
    const int b   = blockIdx.x;
    const int tid = threadIdx.x;

    __shared__ float bins[NP * NT];               // 40 KiB -> 4 blocks/CU exactly

    #pragma unroll
    for (int i = 0; i < NP; ++i) bins[i * NT + tid] = 0.f;
    __syncthreads();

    const v4f* img4 = (const v4f*)x + (size_t)b * IMG4;

    // Main sweep: iteration it -> unit u = it*512 + tid -> float4 idx {2u, 2u+1}.
    // Block step = 16 KB linear; lane l owns bytes [32l, 32l+32) of the step.
    #pragma unroll 4
    for (int it = 0; it < FULLIT; ++it) {
        const unsigned u    = (unsigned)(it * NT + tid);
        const unsigned idx0 = 2u * u;
        const v4f a0 = img4[idx0];
        const v4f a1 = img4[idx0 + 1];
        const unsigned bin0 = bin_of(idx0);
        const unsigned bin1 = bin_of(idx0 + 1);
        const float s0 = (a0.x + a0.y) + (a0.z + a0.w);
        const float s1 = (a1.x + a1.y) + (a1.z + a1.w);
        // In-order per-wave DS ops keep this correct even when bin0 == bin1.
        bins[bin0 * NT + tid] += s0;
        bins[bin1 * NT + tid] += s1;
    }
    if (tid < TAILT) {
        const unsigned u    = (unsigned)(FULLIT * NT + tid);
        const unsigned idx0 = 2u * u;
        const v4f a0 = img4[idx0];
        const v4f a1 = img4[idx0 + 1];
        const unsigned bin0 = bin_of(idx0);
        const unsigned bin1 = bin_of(idx0 + 1);
        bins[bin0 * NT + tid] += (a0.x + a0.y) + (a0.z + a0.w);
        bins[bin1 * NT + tid] += (a1.x + a1.y) + (a1.z + a1.w);
    }
    __syncthreads();

    // Reduce 512 partials per bin: wave w owns bins {w, w+8, w+16}.
    const int wid = tid >> 6, lane = tid & 63;
    float wsum0 = 0.f, wsum1 = 0.f, wsum2 = 0.f;
    {
        float s = 0.f;
        #pragma unroll
        for (int k = 0; k < 8; ++k) s += bins[wid * NT + lane + k * 64];
        #pragma unroll
        for (int off = 32; off >= 1; off >>= 1) s += __shfl_xor(s, off, 64);
        wsum0 = s;
    }
    {
        float s = 0.f;
        #pragma unroll
        for (int k = 0; k < 8; ++k) s += bins[(wid + 8) * NT + lane + k * 64];
        #pragma unroll
        for (int off = 32; off >= 1; off >>= 1) s += __shfl_xor(s, off, 64);
        wsum1 = s;
    }
    if (wid < 4) {
        float s = 0.f;
        #pragma unroll
        for (int k = 0; k < 8; ++k) s += bins[(wid + 16) * NT + lane + k * 64];
        #pragma unroll
        for (int off = 32; off >= 1; off >>= 1) s += __shfl_xor(s, off, 64);
        wsum2 = s;
    }
    __syncthreads();                 // all reads of bins[] done before reuse
    if (lane == 0) {
        bins[wid]     = wsum0;
        bins[wid + 8] = wsum1;
        if (wid < 4) bins[wid + 16] = wsum2;
    }
    __syncthreads();

    // Per-patch scalar MLP: relu(f*w1 + b1) . w2 + b2  (params L2-hot, 2.6 KB)
    if (tid < NP) {
        const float f = bins[tid] * INV_N;        // patch mean
        float acc = 0.f;
        #pragma unroll
        for (int k = 0; k < HID; ++k) {
            const float hh = fmaf(f, w1[tid * HID + k], b1[tid * HID + k]);
            acc = fmaf(fmaxf(hh, 0.f), w2[tid * HID + k], acc);
        }
        const float contrib = acc + b2[tid];
        out[B + (size_t)b * NP + tid] = contrib;  // contribs tail
        bins[64 + tid] = contrib;
    }
    __syncthreads();

    if (tid == 0) {
        float s = 0.f;
        #pragma unroll
        for (int p = 0; p < NP; ++p) s += bins[64 + p];
        out[b] = s;                               // score head
    }
}

extern "C" void kernel_launch(void* const* d_in, const int* in_sizes, int n_in,
                              void* d_out, int out_size, void* d_ws, size_t ws_size,
                              hipStream_t stream)
{
    const float* x  = (const float*)d_in[0];
    const float* w1 = (const float*)d_in[1];
    const float* b1 = (const float*)d_in[2];
    const float* w2 = (const float*)d_in[3];
    const float* b2 = (const float*)d_in[4];
    float* out = (float*)d_out;

    const int B = in_sizes[0] / (CCH * HH * WW);  // 1024

    fused_patch_nam_kernel<<<B, NT, 0, stream>>>(x, w1, b1, w2, b2, out, B);
}